// Round 4
// baseline (68.172 us; speedup 1.0000x reference)
//
#include <hip/hip_runtime.h>
#include <float.h>
#include <math.h>

// B=65536 rows, C=1000 cols, fp32. One wave (64 lanes) per row, persistent
// grid-stride waves with next-row register prefetch (software pipeline).
// grid=1024 blocks (4/CU, all co-resident -> no scheduling tail), 16 rows/wave.
// X streamed once via nontemporal loads (262 MB > L3, zero reuse).
// Per row (row lives in 16 VGPRs/lane):
//   pass1: m = max(x), L = dot(x, wL)        (wL cached in 16 VGPRs per wave)
//   pass2: S = sum exp(x-m), W = sum exp(x-m)*x
//   H_hat = W/S - m - log S ;  T = clip(softplus(L + wH*H_hat/lnC + b), EPS)
//   pass3 (regs only): S2 = sum exp((x-m)/T); nll = log S2 - (x_lab - m)/T
// Mean: per-block double partial -> d_ws, tiny final kernel (1024 vals).

static constexpr int   kC4    = 250;   // float4 per row (1000 floats)
static constexpr int   kBlock = 256;   // 4 waves per block
static constexpr int   kGrid  = 1024;  // 4096 waves -> 16 rows/wave at B=65536
static constexpr int   kWavesTotal = kGrid * (kBlock / 64);
static constexpr float kEps   = 1.1920928955078125e-07f;  // FLT_EPSILON
static constexpr float kLogC  = 6.907755279f;             // ln(1000)

typedef float vfloat4 __attribute__((ext_vector_type(4)));

__device__ __forceinline__ float4 ntload4(const float4* p) {
  vfloat4 v = __builtin_nontemporal_load(reinterpret_cast<const vfloat4*>(p));
  return make_float4(v.x, v.y, v.z, v.w);
}

__device__ __forceinline__ float wred_max(float v) {
#pragma unroll
  for (int off = 32; off > 0; off >>= 1) v = fmaxf(v, __shfl_xor(v, off, 64));
  return v;
}
__device__ __forceinline__ float wred_sum(float v) {
#pragma unroll
  for (int off = 32; off > 0; off >>= 1) v += __shfl_xor(v, off, 64);
  return v;
}

__device__ __forceinline__ void p1_dot_max(const float4 c, const float4 w,
                                           float& L, float& m) {
  L = fmaf(c.x, w.x, L); L = fmaf(c.y, w.y, L);
  L = fmaf(c.z, w.z, L); L = fmaf(c.w, w.w, L);
  m = fmaxf(m, fmaxf(fmaxf(c.x, c.y), fmaxf(c.z, c.w)));
}
__device__ __forceinline__ void p2_sumexp(const float4 c, const float m,
                                          float& S, float& W) {
  float e;
  e = __expf(c.x - m); S += e; W = fmaf(e, c.x, W);
  e = __expf(c.y - m); S += e; W = fmaf(e, c.y, W);
  e = __expf(c.z - m); S += e; W = fmaf(e, c.z, W);
  e = __expf(c.w - m); S += e; W = fmaf(e, c.w, W);
}
__device__ __forceinline__ void p3_sumexp2(const float4 c, const float rT,
                                           const float nmrT, float& S2) {
  S2 += __expf(fmaf(c.x, rT, nmrT)); S2 += __expf(fmaf(c.y, rT, nmrT));
  S2 += __expf(fmaf(c.z, rT, nmrT)); S2 += __expf(fmaf(c.w, rT, nmrT));
}

#define SENT4 make_float4(-FLT_MAX, -FLT_MAX, -FLT_MAX, -FLT_MAX)

__global__ __launch_bounds__(kBlock) void ats_row_kernel(
    const float* __restrict__ X, const int* __restrict__ labels,
    const float* __restrict__ wL, const float* __restrict__ wH,
    const float* __restrict__ bb, double* __restrict__ partial, int B) {
  const int lane   = threadIdx.x & 63;
  const int wib    = threadIdx.x >> 6;                    // wave in block
  const int wid    = blockIdx.x * (kBlock / 64) + wib;    // global wave id
  const bool tailok = lane < (kC4 - 192);                 // lanes 0..57

  // wL cached once per wave (row-invariant), 16 VGPRs
  const float4* WLr = reinterpret_cast<const float4*>(wL);
  const float4 w0 = WLr[lane];
  const float4 w1 = WLr[64 + lane];
  const float4 w2 = WLr[128 + lane];
  const float4 w3 = tailok ? WLr[192 + lane] : make_float4(0.f, 0.f, 0.f, 0.f);
  const float wH0 = wH[0];
  const float b0  = bb[0];

  double acc = 0.0;

  int row = wid;
  float4 c0, c1, c2, c3;
  int labc = 0;
  if (row < B) {  // prefetch first row
    const float4* Xr = reinterpret_cast<const float4*>(X) + (size_t)row * kC4;
    c0 = ntload4(Xr + lane); c1 = ntload4(Xr + 64 + lane);
    c2 = ntload4(Xr + 128 + lane);
    c3 = tailok ? ntload4(Xr + 192 + lane) : SENT4;
    labc = labels[row];
  }

  for (; row < B; row += kWavesTotal) {
    // ---- prefetch next row (issues before the compute below, hides HBM lat)
    const int nrow = row + kWavesTotal;
    float4 n0 = SENT4, n1 = SENT4, n2 = SENT4, n3 = SENT4;
    int labn = 0;
    if (nrow < B) {
      const float4* Xn = reinterpret_cast<const float4*>(X) + (size_t)nrow * kC4;
      n0 = ntload4(Xn + lane); n1 = ntload4(Xn + 64 + lane);
      n2 = ntload4(Xn + 128 + lane);
      n3 = tailok ? ntload4(Xn + 192 + lane) : SENT4;
      labn = labels[nrow];
    }

    // ---- pass1: max + dot (sentinel -FLT_MAX never wins max; w3=0 on tail)
    float L = 0.f, m = -FLT_MAX;
    p1_dot_max(c0, w0, L, m); p1_dot_max(c1, w1, L, m);
    p1_dot_max(c2, w2, L, m); p1_dot_max(c3, w3, L, m);
    m = wred_max(m);

    // ---- pass2: S = sum e, W = sum e*x  (exp underflows to 0 on sentinel)
    float S = 0.f, W = 0.f;
    p2_sumexp(c0, m, S, W); p2_sumexp(c1, m, S, W);
    p2_sumexp(c2, m, S, W); p2_sumexp(c3, m, S, W);
    S = wred_sum(S);
    W = wred_sum(W);
    L = wred_sum(L);

    // ---- x[label]: slot/elem are wave-uniform, one shfl broadcast
    const int c4l = labc >> 2;
    const int sl  = c4l >> 6, ln = c4l & 63, el = labc & 3;
    float4 v = (sl == 0) ? c0 : (sl == 1) ? c1 : (sl == 2) ? c2 : c3;
    float cand = (el == 0) ? v.x : (el == 1) ? v.y : (el == 2) ? v.z : v.w;
    const float xl = __shfl(cand, ln, 64);

    // ---- temperature
    const float Hhat = W / S - m - __logf(S);
    const float a    = L + wH0 * (Hhat / kLogC) + b0;
    const float sp   = (a > 0.f) ? (a + log1pf(__expf(-a))) : log1pf(__expf(a));
    const float T    = fmaxf(sp, kEps);
    const float rT   = 1.0f / T;
    const float nmrT = -m * rT;

    // ---- pass3: S2 = sum exp((x-m)/T)  (registers only)
    float S2 = 0.f;
    p3_sumexp2(c0, rT, nmrT, S2); p3_sumexp2(c1, rT, nmrT, S2);
    p3_sumexp2(c2, rT, nmrT, S2); p3_sumexp2(c3, rT, nmrT, S2);
    S2 = wred_sum(S2);

    const float nll = __logf(S2) - fmaf(xl, rT, nmrT);  // logS2 - (xl-m)/T
    acc += (double)nll;

    // ---- rotate pipeline
    c0 = n0; c1 = n1; c2 = n2; c3 = n3; labc = labn;
  }

  // ---- block partial (all lanes hold identical acc; lane 0 per wave writes)
  __shared__ double sacc[kBlock / 64];
  if (lane == 0) sacc[wib] = acc;
  __syncthreads();
  if (threadIdx.x == 0)
    partial[blockIdx.x] = (sacc[0] + sacc[1]) + (sacc[2] + sacc[3]);
}

__global__ __launch_bounds__(256) void ats_final_kernel(
    const double* __restrict__ partial, float* __restrict__ out, int n, int B) {
  __shared__ double sdata[256];
  double a = 0.0;
  for (int i = threadIdx.x; i < n; i += 256) a += partial[i];
  sdata[threadIdx.x] = a;
  __syncthreads();
#pragma unroll
  for (int s = 128; s > 0; s >>= 1) {
    if ((int)threadIdx.x < s) sdata[threadIdx.x] += sdata[threadIdx.x + s];
    __syncthreads();
  }
  if (threadIdx.x == 0) out[0] = (float)(sdata[0] / (double)B);
}

extern "C" void kernel_launch(void* const* d_in, const int* in_sizes, int n_in,
                              void* d_out, int out_size, void* d_ws, size_t ws_size,
                              hipStream_t stream) {
  (void)n_in; (void)out_size; (void)ws_size;
  const float* X   = (const float*)d_in[0];
  const int*   lab = (const int*)d_in[1];
  const float* wL  = (const float*)d_in[2];
  const float* wH  = (const float*)d_in[3];
  const float* bb  = (const float*)d_in[4];
  const int B = in_sizes[1];            // 65536 labels
  double* partial = (double*)d_ws;      // kGrid doubles = 8 KB scratch
  float* out = (float*)d_out;

  ats_row_kernel<<<kGrid, kBlock, 0, stream>>>(X, lab, wL, wH, bb, partial, B);
  ats_final_kernel<<<1, 256, 0, stream>>>(partial, out, kGrid, B);
}

// Round 5
// 66.140 us; speedup vs baseline: 1.0307x; 1.0307x over previous
//
#include <hip/hip_runtime.h>
#include <float.h>
#include <math.h>

// B=65536 rows, C=1000 cols, fp32. One wave (64 lanes) per row, persistent
// grid-stride waves with next-row register prefetch (software pipeline).
// R5: occupancy experiment — no wL reg-cache (reload per row from L1),
// __launch_bounds__(256,5) caps VGPR ~96 -> 5 waves/SIMD, grid = 5 blk/CU
// exactly (1280), plain (non-NT) loads. X read from HBM exactly once.
// Per row (row lives in 16 VGPRs/lane):
//   pass1: m = max(x), L = dot(x, wL)
//   pass2: S = sum exp(x-m), W = sum exp(x-m)*x
//   H_hat = W/S - m - log S ;  T = clip(softplus(L + wH*H_hat/lnC + b), EPS)
//   pass3 (regs only): S2 = sum exp((x-m)/T); nll = log S2 - (x_lab - m)/T
// Mean: per-block double partial -> d_ws, tiny final kernel (1280 vals).

static constexpr int   kC4    = 250;   // float4 per row (1000 floats)
static constexpr int   kBlock = 256;   // 4 waves per block
static constexpr int   kGrid  = 1280;  // 5 blocks/CU on 256 CUs, all resident
static constexpr int   kWavesTotal = kGrid * (kBlock / 64);
static constexpr float kEps   = 1.1920928955078125e-07f;  // FLT_EPSILON
static constexpr float kLogC  = 6.907755279f;             // ln(1000)

__device__ __forceinline__ float wred_max(float v) {
#pragma unroll
  for (int off = 32; off > 0; off >>= 1) v = fmaxf(v, __shfl_xor(v, off, 64));
  return v;
}
__device__ __forceinline__ float wred_sum(float v) {
#pragma unroll
  for (int off = 32; off > 0; off >>= 1) v += __shfl_xor(v, off, 64);
  return v;
}
// three independent butterflies interleaved (ILP across the bpermute latency)
__device__ __forceinline__ void wred_sum3(float& a, float& b, float& c) {
#pragma unroll
  for (int off = 32; off > 0; off >>= 1) {
    float ta = __shfl_xor(a, off, 64);
    float tb = __shfl_xor(b, off, 64);
    float tc = __shfl_xor(c, off, 64);
    a += ta; b += tb; c += tc;
  }
}

__device__ __forceinline__ void p1_dot_max(const float4 c, const float4 w,
                                           float& L, float& m) {
  L = fmaf(c.x, w.x, L); L = fmaf(c.y, w.y, L);
  L = fmaf(c.z, w.z, L); L = fmaf(c.w, w.w, L);
  m = fmaxf(m, fmaxf(fmaxf(c.x, c.y), fmaxf(c.z, c.w)));
}
__device__ __forceinline__ void p2_sumexp(const float4 c, const float m,
                                          float& S, float& W) {
  float e;
  e = __expf(c.x - m); S += e; W = fmaf(e, c.x, W);
  e = __expf(c.y - m); S += e; W = fmaf(e, c.y, W);
  e = __expf(c.z - m); S += e; W = fmaf(e, c.z, W);
  e = __expf(c.w - m); S += e; W = fmaf(e, c.w, W);
}
__device__ __forceinline__ void p3_sumexp2(const float4 c, const float rT,
                                           const float nmrT, float& S2) {
  S2 += __expf(fmaf(c.x, rT, nmrT)); S2 += __expf(fmaf(c.y, rT, nmrT));
  S2 += __expf(fmaf(c.z, rT, nmrT)); S2 += __expf(fmaf(c.w, rT, nmrT));
}

#define SENT4 make_float4(-FLT_MAX, -FLT_MAX, -FLT_MAX, -FLT_MAX)

__global__ __launch_bounds__(kBlock, 5) void ats_row_kernel(
    const float* __restrict__ X, const int* __restrict__ labels,
    const float* __restrict__ wL, const float* __restrict__ wH,
    const float* __restrict__ bb, double* __restrict__ partial, int B) {
  const int lane   = threadIdx.x & 63;
  const int wib    = threadIdx.x >> 6;                    // wave in block
  const int wid    = blockIdx.x * (kBlock / 64) + wib;    // global wave id
  const bool tailok = lane < (kC4 - 192);                 // lanes 0..57

  const float4* WLr = reinterpret_cast<const float4*>(wL);
  const float wH0 = wH[0];
  const float b0  = bb[0];

  double acc = 0.0;

  int row = wid;
  float4 c0, c1, c2, c3;
  int labc = 0;
  if (row < B) {  // prefetch first row
    const float4* Xr = reinterpret_cast<const float4*>(X) + (size_t)row * kC4;
    c0 = Xr[lane]; c1 = Xr[64 + lane]; c2 = Xr[128 + lane];
    c3 = tailok ? Xr[192 + lane] : SENT4;
    labc = labels[row];
  }

  for (; row < B; row += kWavesTotal) {
    // ---- prefetch next row (issues before the compute below, hides HBM lat)
    const int nrow = row + kWavesTotal;
    float4 n0 = SENT4, n1 = SENT4, n2 = SENT4, n3 = SENT4;
    int labn = 0;
    if (nrow < B) {
      const float4* Xn = reinterpret_cast<const float4*>(X) + (size_t)nrow * kC4;
      n0 = Xn[lane]; n1 = Xn[64 + lane]; n2 = Xn[128 + lane];
      n3 = tailok ? Xn[192 + lane] : SENT4;
      labn = labels[nrow];
    }
    // ---- wL for this row (L1-resident after first touch; 16 transient VGPRs)
    const float4 w0 = WLr[lane];
    const float4 w1 = WLr[64 + lane];
    const float4 w2 = WLr[128 + lane];
    const float4 w3 = tailok ? WLr[192 + lane] : make_float4(0.f, 0.f, 0.f, 0.f);

    // ---- pass1: max + dot (sentinel -FLT_MAX never wins max; w3=0 on tail)
    float L = 0.f, m = -FLT_MAX;
    p1_dot_max(c0, w0, L, m); p1_dot_max(c1, w1, L, m);
    p1_dot_max(c2, w2, L, m); p1_dot_max(c3, w3, L, m);
    m = wred_max(m);

    // ---- pass2: S = sum e, W = sum e*x  (exp underflows to 0 on sentinel)
    float S = 0.f, W = 0.f;
    p2_sumexp(c0, m, S, W); p2_sumexp(c1, m, S, W);
    p2_sumexp(c2, m, S, W); p2_sumexp(c3, m, S, W);
    wred_sum3(S, W, L);

    // ---- x[label]: slot/elem are wave-uniform, one shfl broadcast
    const int c4l = labc >> 2;
    const int sl  = c4l >> 6, ln = c4l & 63, el = labc & 3;
    float4 v = (sl == 0) ? c0 : (sl == 1) ? c1 : (sl == 2) ? c2 : c3;
    float cand = (el == 0) ? v.x : (el == 1) ? v.y : (el == 2) ? v.z : v.w;
    const float xl = __shfl(cand, ln, 64);

    // ---- temperature
    const float Hhat = W / S - m - __logf(S);
    const float a    = L + wH0 * (Hhat / kLogC) + b0;
    const float sp   = (a > 0.f) ? (a + log1pf(__expf(-a))) : log1pf(__expf(a));
    const float T    = fmaxf(sp, kEps);
    const float rT   = 1.0f / T;
    const float nmrT = -m * rT;

    // ---- pass3: S2 = sum exp((x-m)/T)  (registers only)
    float S2 = 0.f;
    p3_sumexp2(c0, rT, nmrT, S2); p3_sumexp2(c1, rT, nmrT, S2);
    p3_sumexp2(c2, rT, nmrT, S2); p3_sumexp2(c3, rT, nmrT, S2);
    S2 = wred_sum(S2);

    const float nll = __logf(S2) - fmaf(xl, rT, nmrT);  // logS2 - (xl-m)/T
    acc += (double)nll;

    // ---- rotate pipeline
    c0 = n0; c1 = n1; c2 = n2; c3 = n3; labc = labn;
  }

  // ---- block partial (all lanes hold identical acc; lane 0 per wave writes)
  __shared__ double sacc[kBlock / 64];
  if (lane == 0) sacc[wib] = acc;
  __syncthreads();
  if (threadIdx.x == 0)
    partial[blockIdx.x] = (sacc[0] + sacc[1]) + (sacc[2] + sacc[3]);
}

__global__ __launch_bounds__(256) void ats_final_kernel(
    const double* __restrict__ partial, float* __restrict__ out, int n, int B) {
  __shared__ double sdata[256];
  double a = 0.0;
  for (int i = threadIdx.x; i < n; i += 256) a += partial[i];
  sdata[threadIdx.x] = a;
  __syncthreads();
#pragma unroll
  for (int s = 128; s > 0; s >>= 1) {
    if ((int)threadIdx.x < s) sdata[threadIdx.x] += sdata[threadIdx.x + s];
    __syncthreads();
  }
  if (threadIdx.x == 0) out[0] = (float)(sdata[0] / (double)B);
}

extern "C" void kernel_launch(void* const* d_in, const int* in_sizes, int n_in,
                              void* d_out, int out_size, void* d_ws, size_t ws_size,
                              hipStream_t stream) {
  (void)n_in; (void)out_size; (void)ws_size;
  const float* X   = (const float*)d_in[0];
  const int*   lab = (const int*)d_in[1];
  const float* wL  = (const float*)d_in[2];
  const float* wH  = (const float*)d_in[3];
  const float* bb  = (const float*)d_in[4];
  const int B = in_sizes[1];            // 65536 labels
  double* partial = (double*)d_ws;      // kGrid doubles = 10 KB scratch
  float* out = (float*)d_out;

  ats_row_kernel<<<kGrid, kBlock, 0, stream>>>(X, lab, wL, wH, bb, partial, B);
  ats_final_kernel<<<1, 256, 0, stream>>>(partial, out, kGrid, B);
}